// Round 3
// baseline (1030.084 us; speedup 1.0000x reference)
//
#include <hip/hip_runtime.h>
#include <math.h>

namespace {
constexpr int kB = 65536;      // rows
constexpr int kC = 300;        // cards/options dim
constexpr int kA = 32;         // archetype dim
constexpr int kCpad = 304;     // padded W rows (300..303 zeroed)
constexpr int kWS = 36;        // W LDS row stride (floats): 16B-aligned b128, <=2-way banks
constexpr int kBlock = 512;
constexpr int kRowsPerBlock = kBlock / 16;  // 32 rows per block
constexpr int kNI = 19;        // ceil(300/16) columns owned per lane
}

// DPP row_ror reductions within each 16-lane DPP row (our thread group == DPP row).
template <int kCtrl>
__device__ __forceinline__ float dpp_rot(float x) {
    int yi = __builtin_amdgcn_update_dpp(0, __builtin_bit_cast(int, x), kCtrl, 0xf, 0xf, false);
    return __builtin_bit_cast(float, yi);
}
__device__ __forceinline__ float rsum16(float x) {
    x += dpp_rot<0x128>(x);   // row_ror:8
    x += dpp_rot<0x124>(x);   // row_ror:4
    x += dpp_rot<0x122>(x);   // row_ror:2
    x += dpp_rot<0x121>(x);   // row_ror:1
    return x;
}
__device__ __forceinline__ float rmax16(float x) {
    x = fmaxf(x, dpp_rot<0x128>(x));
    x = fmaxf(x, dpp_rot<0x124>(x));
    x = fmaxf(x, dpp_rot<0x122>(x));
    x = fmaxf(x, dpp_rot<0x121>(x));
    return x;
}

__global__ __launch_bounds__(kBlock) void draftbot_kernel(
    const float* __restrict__ X,
    const float* __restrict__ W,
    float* __restrict__ out)
{
    __shared__ float w_lds[kCpad * kWS];   // 43,776 B

    const int tid = threadIdx.x;

    // ---- stage W into LDS (zero the 4 pad rows) ----
    for (int j = tid; j < kCpad * kA; j += kBlock) {
        const int c = j >> 5;
        const int a = j & 31;
        w_lds[c * kWS + a] = (c < kC) ? W[j] : 0.0f;
    }
    __syncthreads();

    const int t = tid & 15;                 // lane within 16-thread row group
    const int grp = tid >> 4;               // row group within block
    const size_t row = (size_t)blockIdx.x * kRowsPerBlock + grp;
    const float* __restrict__ xrow = X + row * (2 * kC);

    // ---- load owned cards + option mask (c = t + 16*i) ----
    float cards[kNI];
    unsigned int omask = 0u;
    #pragma unroll
    for (int i = 0; i < kNI; ++i) {
        const int c = t + 16 * i;
        const bool v = (c < kC);
        cards[i] = v ? xrow[kC + c] : 0.0f;
        const float o = v ? xrow[c] : 0.0f;
        if (o != 0.0f) omask |= (1u << i);
    }

    // ---- phase 2: partial ap over owned cards (b128 LDS reads, 4-way bcast) ----
    float ap[kA];
    #pragma unroll
    for (int a = 0; a < kA; ++a) ap[a] = 0.0f;
    #pragma unroll
    for (int i = 0; i < kNI; ++i) {
        const int c = t + 16 * i;
        const float cd = cards[i];
        const float4* __restrict__ wq = reinterpret_cast<const float4*>(&w_lds[c * kWS]);
        #pragma unroll
        for (int q = 0; q < 8; ++q) {
            const float4 w4 = wq[q];
            ap[4 * q + 0] = fmaf(cd, w4.x, ap[4 * q + 0]);
            ap[4 * q + 1] = fmaf(cd, w4.y, ap[4 * q + 1]);
            ap[4 * q + 2] = fmaf(cd, w4.z, ap[4 * q + 2]);
            ap[4 * q + 3] = fmaf(cd, w4.w, ap[4 * q + 3]);
        }
    }
    // ---- phase 3: 16-lane DPP reduce -> every lane holds full ap[], + bias ----
    #pragma unroll
    for (int a = 0; a < kA; ++a) ap[a] = rsum16(ap[a]) + 1.0f;

    // ---- score phase: sc[c] = omask ? ap . W[c,:] : 0  (computed ONCE) ----
    float sc[kNI];
    #pragma unroll
    for (int i = 0; i < kNI; ++i) {
        const int c = t + 16 * i;
        const float4* __restrict__ wq = reinterpret_cast<const float4*>(&w_lds[c * kWS]);
        float e0 = 0.f, e1 = 0.f, e2 = 0.f, e3 = 0.f;
        #pragma unroll
        for (int q = 0; q < 8; ++q) {
            const float4 w4 = wq[q];
            e0 = fmaf(ap[4 * q + 0], w4.x, e0);
            e1 = fmaf(ap[4 * q + 1], w4.y, e1);
            e2 = fmaf(ap[4 * q + 2], w4.z, e2);
            e3 = fmaf(ap[4 * q + 3], w4.w, e3);
        }
        const float dot = (e0 + e1) + (e2 + e3);
        sc[i] = ((omask >> i) & 1u) ? dot : 0.0f;
    }

    // ---- row max (zeros from masked options participate, as in reference) ----
    float m = -INFINITY;
    #pragma unroll
    for (int i = 0; i < kNI; ++i) m = fmaxf(m, sc[i]);
    m = rmax16(m);

    // ---- sum of s * exp(x - M*s) ----
    float S = 0.f;
    #pragma unroll
    for (int i = 0; i < kNI; ++i) {
        const float x = sc[i];
        const float sg = (x > 0.f ? 1.f : 0.f) - (x < 0.f ? 1.f : 0.f);
        S += sg * __expf(fmaf(-m, sg, x));
    }
    S = rsum16(S);
    const float lse = __logf(S);

    // ---- output: s * (x - M*s - lse) ----
    float* __restrict__ orow = out + row * kC;
    #pragma unroll
    for (int i = 0; i < kNI; ++i) {
        const int c = t + 16 * i;
        if (c < kC) {
            const float x = sc[i];
            const float sg = (x > 0.f ? 1.f : 0.f) - (x < 0.f ? 1.f : 0.f);
            orow[c] = sg * (fmaf(-m, sg, x) - lse);
        }
    }
}

extern "C" void kernel_launch(void* const* d_in, const int* in_sizes, int n_in,
                              void* d_out, int out_size, void* d_ws, size_t ws_size,
                              hipStream_t stream) {
    const float* X = (const float*)d_in[0];
    const float* W = (const float*)d_in[1];
    float* out = (float*)d_out;
    dim3 grid(kB / kRowsPerBlock);   // 2048 blocks
    dim3 block(kBlock);              // 512 threads
    hipLaunchKernelGGL(draftbot_kernel, grid, block, 0, stream, X, W, out);
}

// Round 4
// 414.796 us; speedup vs baseline: 2.4833x; 2.4833x over previous
//
#include <hip/hip_runtime.h>
#include <math.h>

namespace {
constexpr int kB = 65536;      // rows
constexpr int kC = 300;        // cards/options dim
constexpr int kA = 32;         // archetype dim
constexpr int kCpad = 304;     // padded W rows (300..303 zeroed)
constexpr int kWS = 36;        // W LDS row stride (floats): 16B-aligned b128, 2-way banks = free
constexpr int kBlock = 256;
constexpr int kRowsPerBlock = kBlock / 16;  // 16 rows per block
constexpr int kNI = 19;        // ceil(300/16) columns owned per lane
}

// DPP row_ror reductions within each 16-lane DPP row (thread group == DPP row).
template <int kCtrl>
__device__ __forceinline__ float dpp_rot(float x) {
    int yi = __builtin_amdgcn_update_dpp(0, __builtin_bit_cast(int, x), kCtrl, 0xf, 0xf, false);
    return __builtin_bit_cast(float, yi);
}
__device__ __forceinline__ float rsum16(float x) {
    x += dpp_rot<0x128>(x);   // row_ror:8
    x += dpp_rot<0x124>(x);   // row_ror:4
    x += dpp_rot<0x122>(x);   // row_ror:2
    x += dpp_rot<0x121>(x);   // row_ror:1
    return x;
}
__device__ __forceinline__ float rmax16(float x) {
    x = fmaxf(x, dpp_rot<0x128>(x));
    x = fmaxf(x, dpp_rot<0x124>(x));
    x = fmaxf(x, dpp_rot<0x122>(x));
    x = fmaxf(x, dpp_rot<0x121>(x));
    return x;
}

__global__ __launch_bounds__(kBlock) void draftbot_kernel(
    const float* __restrict__ X,
    const float* __restrict__ W,
    float* __restrict__ out)
{
    __shared__ float w_lds[kCpad * kWS];   // 43,776 B

    const int tid = threadIdx.x;

    // ---- stage W into LDS (zero the 4 pad rows) ----
    for (int j = tid; j < kCpad * kA; j += kBlock) {
        const int c = j >> 5;
        const int a = j & 31;
        w_lds[c * kWS + a] = (c < kC) ? W[j] : 0.0f;
    }
    __syncthreads();

    const int t = tid & 15;                 // lane within 16-thread row group
    const int grp = tid >> 4;               // row group within block
    const size_t row = (size_t)blockIdx.x * kRowsPerBlock + grp;
    const float* __restrict__ xrow = X + row * (2 * kC);

    // ---- phase 1+2 fused: option mask + partial ap over owned cards ----
    // (card loads folded in: no cards[] array -> lower register pressure)
    float ap[kA];
    #pragma unroll
    for (int a = 0; a < kA; ++a) ap[a] = 0.0f;
    unsigned int omask = 0u;
    #pragma unroll
    for (int i = 0; i < kNI; ++i) {
        const int c = t + 16 * i;
        const bool v = (c < kC);
        const float cd = v ? xrow[kC + c] : 0.0f;
        const float o  = v ? xrow[c] : 0.0f;
        if (o != 0.0f) omask |= (1u << i);
        const float4* __restrict__ wq = reinterpret_cast<const float4*>(&w_lds[c * kWS]);
        #pragma unroll
        for (int q = 0; q < 8; ++q) {
            const float4 w4 = wq[q];
            ap[4 * q + 0] = fmaf(cd, w4.x, ap[4 * q + 0]);
            ap[4 * q + 1] = fmaf(cd, w4.y, ap[4 * q + 1]);
            ap[4 * q + 2] = fmaf(cd, w4.z, ap[4 * q + 2]);
            ap[4 * q + 3] = fmaf(cd, w4.w, ap[4 * q + 3]);
        }
    }
    // ---- 16-lane DPP reduce -> every lane holds full ap[], + bias ----
    #pragma unroll
    for (int a = 0; a < kA; ++a) ap[a] = rsum16(ap[a]) + 1.0f;

    // ---- score phase: sc[c] = omask ? ap . W[c,:] : 0  (computed ONCE) ----
    float sc[kNI];
    #pragma unroll
    for (int i = 0; i < kNI; ++i) {
        const int c = t + 16 * i;
        const float4* __restrict__ wq = reinterpret_cast<const float4*>(&w_lds[c * kWS]);
        float e0 = 0.f, e1 = 0.f, e2 = 0.f, e3 = 0.f;
        #pragma unroll
        for (int q = 0; q < 8; ++q) {
            const float4 w4 = wq[q];
            e0 = fmaf(ap[4 * q + 0], w4.x, e0);
            e1 = fmaf(ap[4 * q + 1], w4.y, e1);
            e2 = fmaf(ap[4 * q + 2], w4.z, e2);
            e3 = fmaf(ap[4 * q + 3], w4.w, e3);
        }
        const float dot = (e0 + e1) + (e2 + e3);
        sc[i] = ((omask >> i) & 1u) ? dot : 0.0f;
    }

    // ---- row max (zeros from masked options participate, as in reference) ----
    float m = -INFINITY;
    #pragma unroll
    for (int i = 0; i < kNI; ++i) m = fmaxf(m, sc[i]);
    m = rmax16(m);

    // ---- sum of s * exp(x - M*s) ----
    float S = 0.f;
    #pragma unroll
    for (int i = 0; i < kNI; ++i) {
        const float x = sc[i];
        const float sg = (x > 0.f ? 1.f : 0.f) - (x < 0.f ? 1.f : 0.f);
        S += sg * __expf(fmaf(-m, sg, x));
    }
    S = rsum16(S);
    const float lse = __logf(S);

    // ---- output: s * (x - M*s - lse) ----
    float* __restrict__ orow = out + row * kC;
    #pragma unroll
    for (int i = 0; i < kNI; ++i) {
        const int c = t + 16 * i;
        if (c < kC) {
            const float x = sc[i];
            const float sg = (x > 0.f ? 1.f : 0.f) - (x < 0.f ? 1.f : 0.f);
            orow[c] = sg * (fmaf(-m, sg, x) - lse);
        }
    }
}

extern "C" void kernel_launch(void* const* d_in, const int* in_sizes, int n_in,
                              void* d_out, int out_size, void* d_ws, size_t ws_size,
                              hipStream_t stream) {
    const float* X = (const float*)d_in[0];
    const float* W = (const float*)d_in[1];
    float* out = (float*)d_out;
    dim3 grid(kB / kRowsPerBlock);   // 4096 blocks
    dim3 block(kBlock);              // 256 threads
    hipLaunchKernelGGL(draftbot_kernel, grid, block, 0, stream, X, W, out);
}

// Round 5
// 117.962 us; speedup vs baseline: 8.7323x; 3.5163x over previous
//
#include <hip/hip_runtime.h>
#include <math.h>

namespace {
constexpr int kB = 65536;      // rows
constexpr int kC = 300;        // cards/options dim
constexpr int kA = 32;         // archetype dim
constexpr int kCpad = 304;     // padded W rows (300..303 zeroed)
constexpr int kWS = 36;        // W LDS row stride (floats): 16B-aligned b128, 2-way banks = free
constexpr int kBlock = 256;
constexpr int kRowsPerBlock = kBlock / 16;  // 16 rows per block
constexpr int kNI = 19;        // ceil(300/16) columns owned per lane
}

// DPP row_ror reductions within each 16-lane DPP row (thread group == DPP row).
template <int kCtrl>
__device__ __forceinline__ float dpp_rot(float x) {
    int yi = __builtin_amdgcn_update_dpp(0, __builtin_bit_cast(int, x), kCtrl, 0xf, 0xf, false);
    return __builtin_bit_cast(float, yi);
}
__device__ __forceinline__ float rsum16(float x) {
    x += dpp_rot<0x128>(x);   // row_ror:8
    x += dpp_rot<0x124>(x);   // row_ror:4
    x += dpp_rot<0x122>(x);   // row_ror:2
    x += dpp_rot<0x121>(x);   // row_ror:1
    return x;
}
__device__ __forceinline__ float rmax16(float x) {
    x = fmaxf(x, dpp_rot<0x128>(x));
    x = fmaxf(x, dpp_rot<0x124>(x));
    x = fmaxf(x, dpp_rot<0x122>(x));
    x = fmaxf(x, dpp_rot<0x121>(x));
    return x;
}

__global__ __launch_bounds__(kBlock) void draftbot_kernel(
    const float* __restrict__ X,
    const float* __restrict__ W,
    float* __restrict__ out)
{
    __shared__ float w_lds[kCpad * kWS];   // 43,776 B

    const int tid = threadIdx.x;
    const int t = tid & 15;                 // lane within 16-thread row group
    const int grp = tid >> 4;               // row group within block
    const size_t row = (size_t)blockIdx.x * kRowsPerBlock + grp;
    const float* __restrict__ xrow = X + row * (2 * kC);

    // ---- phase A: issue all per-row global loads FIRST (latency hides
    //      under W staging + barrier). opts[] dies right after omask.
    float opts[kNI];
    float cards[kNI];
    #pragma unroll
    for (int i = 0; i < kNI; ++i) {
        const int c = t + 16 * i;
        const bool v = (c < kC);
        opts[i]  = v ? xrow[c] : 0.0f;
        cards[i] = v ? xrow[kC + c] : 0.0f;
    }

    // ---- stage W into LDS (zero the 4 pad rows) ----
    for (int j = tid; j < kCpad * kA; j += kBlock) {
        const int c = j >> 5;
        const int a = j & 31;
        w_lds[c * kWS + a] = (c < kC) ? W[j] : 0.0f;
    }
    __syncthreads();

    unsigned int omask = 0u;
    #pragma unroll
    for (int i = 0; i < kNI; ++i)
        if (opts[i] != 0.0f) omask |= (1u << i);

    const float* __restrict__ wl = w_lds + t * kWS;  // lane base (16B-aligned: t*144B)

    // ---- phase B: ap partial accumulation, q OUTER / i inner.
    //      Per q-block: 19 independent b128 + 76 FMA; sched_barrier bounds
    //      in-flight loads so the live set stays well under 256 VGPRs.
    float ap[kA];
    #pragma unroll
    for (int a = 0; a < kA; ++a) ap[a] = 0.0f;
    #pragma unroll
    for (int q = 0; q < 8; ++q) {
        #pragma unroll
        for (int i = 0; i < kNI; ++i) {
            const float4 w4 = *reinterpret_cast<const float4*>(wl + i * 16 * kWS + 4 * q);
            const float cd = cards[i];
            ap[4 * q + 0] = fmaf(cd, w4.x, ap[4 * q + 0]);
            ap[4 * q + 1] = fmaf(cd, w4.y, ap[4 * q + 1]);
            ap[4 * q + 2] = fmaf(cd, w4.z, ap[4 * q + 2]);
            ap[4 * q + 3] = fmaf(cd, w4.w, ap[4 * q + 3]);
        }
        __builtin_amdgcn_sched_barrier(0);
    }

    // ---- 16-lane DPP reduce -> every lane holds full ap[], + bias ----
    #pragma unroll
    for (int a = 0; a < kA; ++a) ap[a] = rsum16(ap[a]) + 1.0f;

    // ---- phase D: scores, q OUTER / i inner, accumulate into sc[i] ----
    float sc[kNI];
    #pragma unroll
    for (int i = 0; i < kNI; ++i) sc[i] = 0.0f;
    #pragma unroll
    for (int q = 0; q < 8; ++q) {
        #pragma unroll
        for (int i = 0; i < kNI; ++i) {
            const float4 w4 = *reinterpret_cast<const float4*>(wl + i * 16 * kWS + 4 * q);
            sc[i] = fmaf(ap[4 * q + 0], w4.x, sc[i]);
            sc[i] = fmaf(ap[4 * q + 1], w4.y, sc[i]);
            sc[i] = fmaf(ap[4 * q + 2], w4.z, sc[i]);
            sc[i] = fmaf(ap[4 * q + 3], w4.w, sc[i]);
        }
        __builtin_amdgcn_sched_barrier(0);
    }
    #pragma unroll
    for (int i = 0; i < kNI; ++i)
        sc[i] = ((omask >> i) & 1u) ? sc[i] : 0.0f;

    // ---- row max (masked zeros participate, as in reference) ----
    float m = -INFINITY;
    #pragma unroll
    for (int i = 0; i < kNI; ++i) m = fmaxf(m, sc[i]);
    m = rmax16(m);

    // ---- sum of s * exp(x - M*s) ----
    float S = 0.f;
    #pragma unroll
    for (int i = 0; i < kNI; ++i) {
        const float x = sc[i];
        const float sg = (x > 0.f ? 1.f : 0.f) - (x < 0.f ? 1.f : 0.f);
        S += sg * __expf(fmaf(-m, sg, x));
    }
    S = rsum16(S);
    const float lse = __logf(S);

    // ---- output: s * (x - M*s - lse) ----
    float* __restrict__ orow = out + row * kC;
    #pragma unroll
    for (int i = 0; i < kNI; ++i) {
        const int c = t + 16 * i;
        if (c < kC) {
            const float x = sc[i];
            const float sg = (x > 0.f ? 1.f : 0.f) - (x < 0.f ? 1.f : 0.f);
            orow[c] = sg * (fmaf(-m, sg, x) - lse);
        }
    }
}

extern "C" void kernel_launch(void* const* d_in, const int* in_sizes, int n_in,
                              void* d_out, int out_size, void* d_ws, size_t ws_size,
                              hipStream_t stream) {
    const float* X = (const float*)d_in[0];
    const float* W = (const float*)d_in[1];
    float* out = (float*)d_out;
    dim3 grid(kB / kRowsPerBlock);   // 4096 blocks
    dim3 block(kBlock);              // 256 threads
    hipLaunchKernelGGL(draftbot_kernel, grid, block, 0, stream, X, W, out);
}

// Round 6
// 72.979 us; speedup vs baseline: 14.1148x; 1.6164x over previous
//
#include <hip/hip_runtime.h>
#include <math.h>

namespace {
constexpr int kB = 65536;      // rows
constexpr int kC = 300;        // cards/options dim
constexpr int kA = 32;         // archetype dim
constexpr int kCpad = 304;     // padded W rows (300..303 zeroed)
constexpr int kWS = 36;        // W LDS row stride (floats): 16B-aligned b128, 2-way banks = free
constexpr int kBlock = 512;
constexpr int kRowsPerBlock = kBlock / 16;  // 32 rows per block
constexpr int kNI = 19;        // ceil(300/16) columns owned per lane
}

// DPP row_ror reductions within each 16-lane DPP row (thread group == DPP row).
template <int kCtrl>
__device__ __forceinline__ float dpp_rot(float x) {
    int yi = __builtin_amdgcn_update_dpp(0, __builtin_bit_cast(int, x), kCtrl, 0xf, 0xf, false);
    return __builtin_bit_cast(float, yi);
}
__device__ __forceinline__ float rsum16(float x) {
    x += dpp_rot<0x128>(x);   // row_ror:8
    x += dpp_rot<0x124>(x);   // row_ror:4
    x += dpp_rot<0x122>(x);   // row_ror:2
    x += dpp_rot<0x121>(x);   // row_ror:1
    return x;
}
__device__ __forceinline__ float rmax16(float x) {
    x = fmaxf(x, dpp_rot<0x128>(x));
    x = fmaxf(x, dpp_rot<0x124>(x));
    x = fmaxf(x, dpp_rot<0x122>(x));
    x = fmaxf(x, dpp_rot<0x121>(x));
    return x;
}

__global__ __launch_bounds__(kBlock) void draftbot_kernel(
    const float* __restrict__ X,
    const float* __restrict__ W,
    float* __restrict__ out)
{
    __shared__ float w_lds[kCpad * kWS];   // 43,776 B -> 3 blocks/CU, 24 waves/CU

    const int tid = threadIdx.x;
    const int t = tid & 15;                 // lane within 16-thread row group
    const int grp = tid >> 4;               // row group within block
    const size_t row = (size_t)blockIdx.x * kRowsPerBlock + grp;
    const float* __restrict__ xrow = X + row * (2 * kC);

    // ---- phase A: issue all per-row global loads FIRST (latency hides
    //      under W staging + barrier). opts[] dies right after omask.
    float opts[kNI];
    float cards[kNI];
    #pragma unroll
    for (int i = 0; i < kNI; ++i) {
        const int c = t + 16 * i;
        const bool v = (c < kC);
        opts[i]  = v ? xrow[c] : 0.0f;
        cards[i] = v ? xrow[kC + c] : 0.0f;
    }

    // ---- stage W into LDS, vectorized (float4), zero the 4 pad rows ----
    {
        const float4* __restrict__ W4 = reinterpret_cast<const float4*>(W);
        #pragma unroll
        for (int f = tid; f < (kCpad * kA) / 4; f += kBlock) {   // 2432 float4s
            float4 v;
            if (f < (kC * kA) / 4) v = W4[f];
            else { v.x = v.y = v.z = v.w = 0.0f; }
            const int c = f >> 3;            // 8 float4 per W row
            const int a4 = (f & 7) * 4;      // float offset within row
            *reinterpret_cast<float4*>(&w_lds[c * kWS + a4]) = v;
        }
    }
    __syncthreads();

    unsigned int omask = 0u;
    #pragma unroll
    for (int i = 0; i < kNI; ++i)
        if (opts[i] != 0.0f) omask |= (1u << i);

    const float* __restrict__ wl = w_lds + t * kWS;  // lane base (16B-aligned: t*144B)

    // ---- phase B: ap partial accumulation, q OUTER / i inner.
    //      Per q-block: 19 independent b128 + 76 FMA; sched_barrier bounds
    //      in-flight loads so the live set stays well under the VGPR cap.
    float ap[kA];
    #pragma unroll
    for (int a = 0; a < kA; ++a) ap[a] = 0.0f;
    #pragma unroll
    for (int q = 0; q < 8; ++q) {
        #pragma unroll
        for (int i = 0; i < kNI; ++i) {
            const float4 w4 = *reinterpret_cast<const float4*>(wl + i * 16 * kWS + 4 * q);
            const float cd = cards[i];
            ap[4 * q + 0] = fmaf(cd, w4.x, ap[4 * q + 0]);
            ap[4 * q + 1] = fmaf(cd, w4.y, ap[4 * q + 1]);
            ap[4 * q + 2] = fmaf(cd, w4.z, ap[4 * q + 2]);
            ap[4 * q + 3] = fmaf(cd, w4.w, ap[4 * q + 3]);
        }
        __builtin_amdgcn_sched_barrier(0);
    }

    // ---- 16-lane DPP reduce -> every lane holds full ap[], + bias ----
    #pragma unroll
    for (int a = 0; a < kA; ++a) ap[a] = rsum16(ap[a]) + 1.0f;

    // ---- phase D: scores, q OUTER / i inner, accumulate into sc[i] ----
    float sc[kNI];
    #pragma unroll
    for (int i = 0; i < kNI; ++i) sc[i] = 0.0f;
    #pragma unroll
    for (int q = 0; q < 8; ++q) {
        #pragma unroll
        for (int i = 0; i < kNI; ++i) {
            const float4 w4 = *reinterpret_cast<const float4*>(wl + i * 16 * kWS + 4 * q);
            sc[i] = fmaf(ap[4 * q + 0], w4.x, sc[i]);
            sc[i] = fmaf(ap[4 * q + 1], w4.y, sc[i]);
            sc[i] = fmaf(ap[4 * q + 2], w4.z, sc[i]);
            sc[i] = fmaf(ap[4 * q + 3], w4.w, sc[i]);
        }
        __builtin_amdgcn_sched_barrier(0);
    }
    #pragma unroll
    for (int i = 0; i < kNI; ++i)
        sc[i] = ((omask >> i) & 1u) ? sc[i] : 0.0f;

    // ---- row max (masked zeros participate, as in reference) ----
    float m = -INFINITY;
    #pragma unroll
    for (int i = 0; i < kNI; ++i) m = fmaxf(m, sc[i]);
    m = rmax16(m);

    // ---- sum of s * exp(x - M*s) ----
    float S = 0.f;
    #pragma unroll
    for (int i = 0; i < kNI; ++i) {
        const float x = sc[i];
        const float sg = (x > 0.f ? 1.f : 0.f) - (x < 0.f ? 1.f : 0.f);
        S += sg * __expf(fmaf(-m, sg, x));
    }
    S = rsum16(S);
    const float lse = __logf(S);

    // ---- output: s * (x - M*s - lse) ----
    float* __restrict__ orow = out + row * kC;
    #pragma unroll
    for (int i = 0; i < kNI; ++i) {
        const int c = t + 16 * i;
        if (c < kC) {
            const float x = sc[i];
            const float sg = (x > 0.f ? 1.f : 0.f) - (x < 0.f ? 1.f : 0.f);
            orow[c] = sg * (fmaf(-m, sg, x) - lse);
        }
    }
}

extern "C" void kernel_launch(void* const* d_in, const int* in_sizes, int n_in,
                              void* d_out, int out_size, void* d_ws, size_t ws_size,
                              hipStream_t stream) {
    const float* X = (const float*)d_in[0];
    const float* W = (const float*)d_in[1];
    float* out = (float*)d_out;
    dim3 grid(kB / kRowsPerBlock);   // 2048 blocks
    dim3 block(kBlock);              // 512 threads
    hipLaunchKernelGGL(draftbot_kernel, grid, block, 0, stream, X, W, out);
}